// Round 16
// baseline (26.981 us; speedup 1.0000x reference)
//
#include <hip/hip_runtime.h>
#include <hip/hip_fp16.h>
#include <math.h>

// T=24, NSEQ=16384, FS=64, FM=16, FC=16 -> I=96; H=32.
//
// R16 = R14 + 4-slot ring (producer one interval ahead -> consumer ds_reads
// fully off the serial path) + standard clamp-free gates.
//  - block = 128 thr: wave0 = CONSUMER (all 32 units, in-register sigma
//    recurrence; reads step k+1's xacc tiles during interval k),
//    wave1 = PRODUCER (fills step k+2 during interval k into a 4-slot ring).
//  - Ring slot s holds step s mod 4; write(step k+2, interval k) vs
//    read(step k+1, interval k): >=2 barriers apart -> race-free.
//  - Gates: R=exp2(-dr); r=rcp(1+R); Y=fma(r,th,ti); e=exp2(-Y);
//    n=2*rcp(1+e)-1; z=rcp(1+exp2(-dz)); h'=n+z*(h-n). Inf-safe, no clamps.
//  - Weights gathered directly (R12-validated), RN-pack, log2e-scaled.
//  - 1024 blocks = 2048 waves = 2/SIMD; LDS 30.7 KB -> 4 blocks/CU.

typedef __attribute__((ext_vector_type(8))) _Float16 half8;
typedef __attribute__((ext_vector_type(4))) float f32x4;
typedef __attribute__((ext_vector_type(4))) unsigned int uix4;

#define NSEQ 16384
#define TSTEPS 24
#define LOG2E 1.44269504088896340736f

__device__ __forceinline__ float exp2_fast(float x) {
#if __has_builtin(__builtin_amdgcn_exp2f)
  return __builtin_amdgcn_exp2f(x);
#else
  return __expf(x * 0.6931471805599453f);
#endif
}

__device__ __forceinline__ unsigned int pk_f16(float a, float b) {
#if __has_builtin(__builtin_amdgcn_cvt_pkrtz)
  auto r = __builtin_amdgcn_cvt_pkrtz(a, b);
  return __builtin_bit_cast(unsigned int, r);
#else
  return (unsigned)__half_as_ushort(__float2half(a)) |
         ((unsigned)__half_as_ushort(__float2half(b)) << 16);
#endif
}
__device__ __forceinline__ unsigned int pk_f16_rn(float a, float b) {
  return (unsigned)__half_as_ushort(__float2half(a)) |
         ((unsigned)__half_as_ushort(__float2half(b)) << 16);
}
__device__ __forceinline__ half8 mk_h8(unsigned int a, unsigned int b,
                                       unsigned int c, unsigned int d) {
  uix4 v = {a, b, c, d};
  return __builtin_bit_cast(half8, v);
}
__device__ __forceinline__ f32x4 mfma_h(half8 a, half8 b, f32x4 c) {
  return __builtin_amdgcn_mfma_f32_16x16x32_f16(a, b, c, 0, 0, 0);
}

// workgroup barrier draining LDS ops only
__device__ __forceinline__ void barrier_lds() {
  asm volatile("s_waitcnt lgkmcnt(0)" ::: "memory");
  __builtin_amdgcn_s_barrier();
}

__global__ __launch_bounds__(128, 4)
void gru12(const float* __restrict__ spatial,
           const float* __restrict__ met,
           const float* __restrict__ ctx,
           const float* __restrict__ W_ih,
           const float* __restrict__ W_hh,
           const float* __restrict__ b_ih,
           const float* __restrict__ b_hh,
           const float* __restrict__ Wp,
           float* __restrict__ out) {
  // 4-slot ring: [slot][tile j][seq 16][20-pad f32] = 30.7 KB
  __shared__ float xls[4][6][16][20];

  const int tid = threadIdx.x;
  const int lane = tid & 63;
  const int wv = tid >> 6;         // 0 = consumer, 1 = producer
  const int l15 = lane & 15;
  const int c = lane >> 4;         // 0..3
  const int seq = blockIdx.x * 16 + l15;
  const f32x4 zero4 = {0.f, 0.f, 0.f, 0.f};

  if (wv == 1) {
    // ======================= PRODUCER =======================
    half8 wmc[6];
    f32x4 acc_i[6];
#pragma unroll
    for (int j = 0; j < 6; ++j) {
      const float sc = (j < 4) ? LOG2E : (2.0f * LOG2E);
      const float* mr = W_ih + (size_t)(j * 16 + l15) * 96 + 64 + c * 8;
      float4 wa = *(const float4*)mr;
      float4 wb = *(const float4*)(mr + 4);
      wmc[j] = mk_h8(pk_f16_rn(wa.x * sc, wa.y * sc),
                     pk_f16_rn(wa.z * sc, wa.w * sc),
                     pk_f16_rn(wb.x * sc, wb.y * sc),
                     pk_f16_rn(wb.z * sc, wb.w * sc));
      const int rowb = j * 16 + 4 * c;
      float4 vih = *(const float4*)(b_ih + rowb);
      if (j < 4) {
        float4 vhh = *(const float4*)(b_hh + rowb);
        acc_i[j][0] = (vih.x + vhh.x) * sc; acc_i[j][1] = (vih.y + vhh.y) * sc;
        acc_i[j][2] = (vih.z + vhh.z) * sc; acc_i[j][3] = (vih.w + vhh.w) * sc;
      } else {
        acc_i[j][0] = vih.x * sc; acc_i[j][1] = vih.y * sc;
        acc_i[j][2] = vih.z * sc; acc_i[j][3] = vih.w * sc;
      }
    }
#pragma unroll
    for (int kt = 0; kt < 2; ++kt) {
      const float* sp = spatial + (size_t)seq * 64 + kt * 32 + c * 8;
      float4 a0 = *(const float4*)sp;
      float4 a1 = *(const float4*)(sp + 4);
      half8 sf = mk_h8(pk_f16(a0.x, a0.y), pk_f16(a0.z, a0.w),
                       pk_f16(a1.x, a1.y), pk_f16(a1.z, a1.w));
#pragma unroll
      for (int j = 0; j < 6; ++j) {
        const float sc = (j < 4) ? LOG2E : (2.0f * LOG2E);
        const float* wr = W_ih + (size_t)(j * 16 + l15) * 96 + kt * 32 + c * 8;
        float4 wa = *(const float4*)wr;
        float4 wb = *(const float4*)(wr + 4);
        half8 wsp = mk_h8(pk_f16_rn(wa.x * sc, wa.y * sc),
                          pk_f16_rn(wa.z * sc, wa.w * sc),
                          pk_f16_rn(wb.x * sc, wb.y * sc),
                          pk_f16_rn(wb.z * sc, wb.w * sc));
        acc_i[j] = mfma_h(wsp, sf, acc_i[j]);
      }
    }
    const float* lptr = ((c < 2) ? met : ctx) + (size_t)seq * 16 + (c & 1) * 8;

    auto fill = [&](int slot, float4 xa, float4 xb) {
      half8 xf = mk_h8(pk_f16(xa.x, xa.y), pk_f16(xa.z, xa.w),
                       pk_f16(xb.x, xb.y), pk_f16(xb.z, xb.w));
#pragma unroll
      for (int j = 0; j < 6; ++j) {
        f32x4 D = mfma_h(wmc[j], xf, acc_i[j]);
        *(f32x4*)&xls[slot][j][l15][c * 4] = D;
      }
    };
    auto ldx = [&](int t, float4& a, float4& b) {
      const float* p = lptr + (size_t)t * NSEQ * 16;
      a = *(const float4*)p; b = *(const float4*)(p + 4);
    };

    // prologue: fill steps 0,1 into slots 0,1; stage x(2),x(3)
    {
      float4 a0, b0, a1, b1;
      ldx(0, a0, b0); ldx(1, a1, b1);
      fill(0, a0, b0); fill(1, a1, b1);
    }
    float4 pAa, pAb, pBa, pBb;           // pA: even-k fills, pB: odd-k fills
    ldx(2, pAa, pAb); ldx(3, pBa, pBb);

    barrier_lds();                       // barrier 0: steps 0,1 visible

#pragma unroll 2
    for (int kk = 0; kk < 12; ++kk) {
      {                                   // k = 2kk: fill step k+2 (even slot)
        const int k = 2 * kk;
        if (k + 2 < TSTEPS) fill((k + 2) & 3, pAa, pAb);
        int tf = (k + 4 < TSTEPS) ? (k + 4) : (TSTEPS - 1);
        ldx(tf, pAa, pAb);
        barrier_lds();
      }
      {                                   // k = 2kk+1
        const int k = 2 * kk + 1;
        if (k + 2 < TSTEPS) fill((k + 2) & 3, pBa, pBb);
        int tf = (k + 4 < TSTEPS) ? (k + 4) : (TSTEPS - 1);
        ldx(tf, pBa, pBb);
        barrier_lds();
      }
    }
    // producer done
  } else {
    // ======================= CONSUMER =======================
    __builtin_amdgcn_s_setprio(1);
    half8 whh[6];
#pragma unroll
    for (int j = 0; j < 6; ++j) {
      const float sc = (j < 4) ? LOG2E : (2.0f * LOG2E);
      const float* wr = W_hh + (size_t)(j * 16 + l15) * 32;
      float4 a = *(const float4*)(wr + 4 * c);
      float4 b = *(const float4*)(wr + 16 + 4 * c);
      whh[j] = mk_h8(pk_f16_rn(a.x * sc, a.y * sc),
                     pk_f16_rn(a.z * sc, a.w * sc),
                     pk_f16_rn(b.x * sc, b.y * sc),
                     pk_f16_rn(b.z * sc, b.w * sc));
    }
    f32x4 bhnA, bhnB;
    {
      float4 va = *(const float4*)(b_hh + 64 + 4 * c);
      float4 vb = *(const float4*)(b_hh + 64 + 16 + 4 * c);
      bhnA[0] = 2.0f * LOG2E * va.x; bhnA[1] = 2.0f * LOG2E * va.y;
      bhnA[2] = 2.0f * LOG2E * va.z; bhnA[3] = 2.0f * LOG2E * va.w;
      bhnB[0] = 2.0f * LOG2E * vb.x; bhnB[1] = 2.0f * LOG2E * vb.y;
      bhnB[2] = 2.0f * LOG2E * vb.z; bhnB[3] = 2.0f * LOG2E * vb.w;
    }
    float hst[8];
#pragma unroll
    for (int i = 0; i < 8; ++i) hst[i] = 0.0f;
    half8 fh = mk_h8(0u, 0u, 0u, 0u);

    // standard clamp-free gates; updates hst/fh
    auto do_step = [&](f32x4 xr0, f32x4 xr1, f32x4 xz0, f32x4 xz1,
                       f32x4 ti0, f32x4 ti1) {
      f32x4 dr0 = mfma_h(whh[0], fh, xr0);
      f32x4 dr1 = mfma_h(whh[1], fh, xr1);
      f32x4 dz0 = mfma_h(whh[2], fh, xz0);
      f32x4 dz1 = mfma_h(whh[3], fh, xz1);
      f32x4 th0 = mfma_h(whh[4], fh, bhnA);
      f32x4 th1 = mfma_h(whh[5], fh, bhnB);
      float hv_[8];
#pragma unroll
      for (int jj = 0; jj < 2; ++jj) {
        f32x4 ddr = jj ? dr1 : dr0;
        f32x4 ddz = jj ? dz1 : dz0;
        f32x4 tth = jj ? th1 : th0;
        f32x4 tti = jj ? ti1 : ti0;
#pragma unroll
        for (int q = 0; q < 4; ++q) {
          const int i = jj * 4 + q;
          float R = exp2_fast(-ddr[q]);
          float r = __builtin_amdgcn_rcpf(1.0f + R);
          float E = exp2_fast(-ddz[q]);
          float z = __builtin_amdgcn_rcpf(1.0f + E);
          float Y = fmaf(r, tth[q], tti[q]);
          float e = exp2_fast(-Y);
          float s = __builtin_amdgcn_rcpf(1.0f + e);
          float n = fmaf(2.0f, s, -1.0f);
          float hv = fmaf(z, hst[i] - n, n);
          hst[i] = hv;
          hv_[i] = hv;
        }
      }
      fh = mk_h8(pk_f16(hv_[0], hv_[1]), pk_f16(hv_[2], hv_[3]),
                 pk_f16(hv_[4], hv_[5]), pk_f16(hv_[6], hv_[7]));
    };

    barrier_lds();                       // barrier 0: steps 0,1 visible

    // prologue read: step 0 -> A (on-path once)
    f32x4 A0, A1, A2, A3, A4, A5, B0, B1, B2, B3, B4, B5;
    A0 = *(const f32x4*)&xls[0][0][l15][c * 4];
    A1 = *(const f32x4*)&xls[0][1][l15][c * 4];
    A2 = *(const f32x4*)&xls[0][2][l15][c * 4];
    A3 = *(const f32x4*)&xls[0][3][l15][c * 4];
    A4 = *(const f32x4*)&xls[0][4][l15][c * 4];
    A5 = *(const f32x4*)&xls[0][5][l15][c * 4];

#pragma unroll 2
    for (int kk = 0; kk < 12; ++kk) {
      {                                   // k = 2kk: read k+1 -> B, compute A
        const int k = 2 * kk;
        const int sl = (k + 1) & 3;
        B0 = *(const f32x4*)&xls[sl][0][l15][c * 4];
        B1 = *(const f32x4*)&xls[sl][1][l15][c * 4];
        B2 = *(const f32x4*)&xls[sl][2][l15][c * 4];
        B3 = *(const f32x4*)&xls[sl][3][l15][c * 4];
        B4 = *(const f32x4*)&xls[sl][4][l15][c * 4];
        B5 = *(const f32x4*)&xls[sl][5][l15][c * 4];
        do_step(A0, A1, A2, A3, A4, A5);
        barrier_lds();
      }
      {                                   // k = 2kk+1: read k+1 -> A, compute B
        const int k = 2 * kk + 1;
        if (k + 1 < TSTEPS) {
          const int sl = (k + 1) & 3;
          A0 = *(const f32x4*)&xls[sl][0][l15][c * 4];
          A1 = *(const f32x4*)&xls[sl][1][l15][c * 4];
          A2 = *(const f32x4*)&xls[sl][2][l15][c * 4];
          A3 = *(const f32x4*)&xls[sl][3][l15][c * 4];
          A4 = *(const f32x4*)&xls[sl][4][l15][c * 4];
          A5 = *(const f32x4*)&xls[sl][5][l15][c * 4];
        }
        do_step(B0, B1, B2, B3, B4, B5);
        barrier_lds();
      }
    }

    // ---- projection: all 4 f-tiles; Wp gathered (sigma cols), f16 2-term ----
#pragma unroll
    for (int pt = 0; pt < 4; ++pt) {
      const int frow = pt * 16 + l15;
      const float* wpb = Wp + frow;
      float v[8];
#pragma unroll
      for (int e = 0; e < 8; ++e) {
        int col = (e < 4) ? (4 * c + e) : (16 + 4 * c + (e - 4));
        v[e] = wpb[(size_t)col * 64];
      }
      unsigned int uh[4], ul[4];
#pragma unroll
      for (int e2 = 0; e2 < 4; ++e2) {
        float va = v[2 * e2], vb = v[2 * e2 + 1];
        __half ha = __float2half(va), hb = __float2half(vb);
        float la = va - __half2float(ha), lb = vb - __half2float(hb);
        uh[e2] = (unsigned)__half_as_ushort(ha) |
                 ((unsigned)__half_as_ushort(hb) << 16);
        ul[e2] = pk_f16_rn(la, lb);
      }
      half8 wph = mk_h8(uh[0], uh[1], uh[2], uh[3]);
      half8 wpl = mk_h8(ul[0], ul[1], ul[2], ul[3]);
      f32x4 o = mfma_h(wph, fh, zero4);
      o = mfma_h(wpl, fh, o);
      float* op = out + (size_t)seq * 64 + pt * 16 + 4 * c;
      *(float4*)op = make_float4(o[0], o[1], o[2], o[3]);
    }
    __builtin_amdgcn_s_setprio(0);
  }
}

extern "C" void kernel_launch(void* const* d_in, const int* in_sizes, int n_in,
                              void* d_out, int out_size, void* d_ws, size_t ws_size,
                              hipStream_t stream) {
  const float* spatial = (const float*)d_in[0];
  const float* met     = (const float*)d_in[1];
  const float* ctx     = (const float*)d_in[2];
  const float* W_ih    = (const float*)d_in[3];
  const float* W_hh    = (const float*)d_in[4];
  const float* b_ih    = (const float*)d_in[5];
  const float* b_hh    = (const float*)d_in[6];
  const float* Wp      = (const float*)d_in[7];
  float* out = (float*)d_out;

  hipLaunchKernelGGL(gru12, dim3(1024), dim3(128), 0, stream,
                     spatial, met, ctx, W_ih, W_hh, b_ih, b_hh, Wp, out);
}